// Round 1
// baseline (694.041 us; speedup 1.0000x reference)
//
#include <hip/hip_runtime.h>

// Problem constants (fixed by the reference): query (32,1,1024) f32, keys (32,4096,1024) f32
#define BATCH 32
#define S 4096
#define H 1024
#define H4 (H / 4)            // 256 float4 per row
#define NCHUNK 32             // S-chunks per batch -> grid = 32*32 = 1024 blocks (4/CU)
#define KPC (S / NCHUNK)      // 128 keys per chunk
#define BLOCK 256
#define NWAVE (BLOCK / 64)    // 4 waves
#define KPW (KPC / NWAVE)     // 32 keys per wave

// clang ext_vector_type: layout-identical to float4, full vector arithmetic.
typedef float vfloat4 __attribute__((ext_vector_type(4)));

// Pass 1: fused scores + online-softmax partial context. One read of keys total.
// 2-row register pipeline: rows i,i+1 resident, rows i+2,i+3 in flight (8 KB/wave
// outstanding). Plain loads (no NT) so L2/L3 absorb burst latency.
__global__ __launch_bounds__(BLOCK) void attn_pass1(
    const float* __restrict__ query, const float* __restrict__ keys,
    float* __restrict__ scores,         // raw scores -> d_out weights region (normalized by pass 2)
    float* __restrict__ po,             // [BATCH][NCHUNK][H] partial context (unnormalized)
    float* __restrict__ pm,             // [BATCH][NCHUNK] partial max
    float* __restrict__ pl)             // [BATCH][NCHUNK] partial sum
{
  const int chunk = blockIdx.x;
  const int b     = blockIdx.y;
  const int lane  = threadIdx.x & 63;
  const int wave  = threadIdx.x >> 6;

  // Query fragment: 16 floats/lane, same layout as key fragments.
  const vfloat4* q4 = (const vfloat4*)(query + (size_t)b * H);
  const vfloat4 q0 = q4[lane], q1 = q4[lane + 64], q2 = q4[lane + 128], q3 = q4[lane + 192];

  const int s0 = chunk * KPC + wave * KPW;
  const vfloat4* base = (const vfloat4*)(keys + ((size_t)b * S + s0) * (size_t)H);

  // Prologue: rows 0 and 1 into registers.
  vfloat4 a0 = base[lane],       a1 = base[lane + 64],
          a2 = base[lane + 128], a3 = base[lane + 192];
  const vfloat4* pB0 = base + H4;
  vfloat4 b0 = pB0[lane],       b1 = pB0[lane + 64],
          b2 = pB0[lane + 128], b3 = pB0[lane + 192];

  float m = -3.0e38f, l = 0.0f;
  vfloat4 o0 = {0,0,0,0}, o1 = {0,0,0,0}, o2 = {0,0,0,0}, o3 = {0,0,0,0};

  for (int i = 0; i < KPW; i += 2) {
    // Prefetch rows i+2, i+3. Clamped pointer on the tail: re-reads row 0
    // (L2-hit now that loads are cached) — keeps the loads unconditional and
    // exec-mask-free so they stay hoisted above the compute chain.
    const vfloat4* nA = (i + 2 < KPW) ? base + (size_t)(i + 2) * H4 : base;
    const vfloat4* nB = (i + 3 < KPW) ? base + (size_t)(i + 3) * H4 : base;
    const vfloat4 na0 = nA[lane],       na1 = nA[lane + 64],
                  na2 = nA[lane + 128], na3 = nA[lane + 192];
    const vfloat4 nb0 = nB[lane],       nb1 = nB[lane + 64],
                  nb2 = nB[lane + 128], nb3 = nB[lane + 192];

    // Two independent dot products -> two independent shuffle-reduce chains
    // (the scheduler interleaves them, halving effective cross-lane latency).
    float dA = a0.x*q0.x + a0.y*q0.y + a0.z*q0.z + a0.w*q0.w
             + a1.x*q1.x + a1.y*q1.y + a1.z*q1.z + a1.w*q1.w
             + a2.x*q2.x + a2.y*q2.y + a2.z*q2.z + a2.w*q2.w
             + a3.x*q3.x + a3.y*q3.y + a3.z*q3.z + a3.w*q3.w;
    float dB = b0.x*q0.x + b0.y*q0.y + b0.z*q0.z + b0.w*q0.w
             + b1.x*q1.x + b1.y*q1.y + b1.z*q1.z + b1.w*q1.w
             + b2.x*q2.x + b2.y*q2.y + b2.z*q2.z + b2.w*q2.w
             + b3.x*q3.x + b3.y*q3.y + b3.z*q3.z + b3.w*q3.w;
    #pragma unroll
    for (int off = 1; off < 64; off <<= 1) {
      dA += __shfl_xor(dA, off);
      dB += __shfl_xor(dB, off);
    }

    if (lane == 0) {
      scores[(size_t)b * S + (s0 + i)]     = dA;
      scores[(size_t)b * S + (s0 + i + 1)] = dB;
    }

    // Fused 2-row online-softmax update: one rescale per two rows.
    const float mn = fmaxf(fmaxf(m, dA), dB);     // v_max3_f32
    const float sc = __expf(m  - mn);             // 0 on first iter (m = -3e38)
    const float pA = __expf(dA - mn);
    const float pB = __expf(dB - mn);
    l  = l * sc + pA + pB;
    o0 = o0*sc + pA*a0 + pB*b0;
    o1 = o1*sc + pA*a1 + pB*b1;
    o2 = o2*sc + pA*a2 + pB*b2;
    o3 = o3*sc + pA*a3 + pB*b3;
    m = mn;

    a0 = na0; a1 = na1; a2 = na2; a3 = na3;
    b0 = nb0; b1 = nb1; b2 = nb2; b3 = nb3;
  }

  // Combine the 4 waves' (m, l, o) within the block via LDS.
  __shared__ float lds_o[NWAVE][H];     // 16 KiB
  __shared__ float lds_m[NWAVE], lds_l[NWAVE];
  vfloat4* lo = (vfloat4*)lds_o[wave];
  lo[lane] = o0; lo[lane + 64] = o1; lo[lane + 128] = o2; lo[lane + 192] = o3;
  if (lane == 0) { lds_m[wave] = m; lds_l[wave] = l; }
  __syncthreads();

  const int t = threadIdx.x;
  const float bm = fmaxf(fmaxf(lds_m[0], lds_m[1]), fmaxf(lds_m[2], lds_m[3]));
  float bl = 0.0f;
  vfloat4 acc = {0,0,0,0};
  #pragma unroll
  for (int w = 0; w < NWAVE; ++w) {
    const float scw = __expf(lds_m[w] - bm);
    bl += lds_l[w] * scw;
    const vfloat4 ow = ((const vfloat4*)lds_o[w])[t];
    acc += ow * scw;
  }
  ((vfloat4*)po)[((size_t)b * NCHUNK + chunk) * H4 + t] = acc;
  if (t == 0) { pm[b * NCHUNK + chunk] = bm; pl[b * NCHUNK + chunk] = bl; }
}

// Pass 2: merge the NCHUNK chunk partials per batch, emit context and normalized weights.
__global__ __launch_bounds__(256) void attn_pass2(
    const float* __restrict__ po, const float* __restrict__ pm, const float* __restrict__ pl,
    float* __restrict__ ctx, float* __restrict__ wts)
{
  const int b = blockIdx.x;
  const int t = threadIdx.x;
  __shared__ float s_scale[NCHUNK];
  __shared__ float s_m, s_invl;
  if (t == 0) {
    float m = -3.0e38f;
    for (int j = 0; j < NCHUNK; ++j) m = fmaxf(m, pm[b * NCHUNK + j]);
    float l = 0.0f;
    for (int j = 0; j < NCHUNK; ++j) {
      const float sc = __expf(pm[b * NCHUNK + j] - m);
      s_scale[j] = sc;
      l += pl[b * NCHUNK + j] * sc;
    }
    s_m = m; s_invl = 1.0f / l;
  }
  __syncthreads();
  const float m = s_m, invl = s_invl;

  vfloat4 acc = {0,0,0,0};
  for (int j = 0; j < NCHUNK; ++j) {
    const vfloat4 ow = ((const vfloat4*)po)[((size_t)b * NCHUNK + j) * H4 + t];
    acc += ow * s_scale[j];
  }
  acc *= invl;
  ((vfloat4*)ctx)[(size_t)b * H4 + t] = acc;

  // Normalize stored raw scores in place.
  for (int s = t; s < S; s += 256) {
    const float sc = wts[(size_t)b * S + s];
    wts[(size_t)b * S + s] = __expf(sc - m) * invl;
  }
}

extern "C" void kernel_launch(void* const* d_in, const int* in_sizes, int n_in,
                              void* d_out, int out_size, void* d_ws, size_t ws_size,
                              hipStream_t stream) {
  const float* query = (const float*)d_in[0];   // 32*1*1024
  const float* keys  = (const float*)d_in[1];   // 32*4096*1024

  float* ctx = (float*)d_out;                   // context: first 32*1024 floats
  float* wts = (float*)d_out + BATCH * H;       // weights: next 32*4096 floats

  float* po = (float*)d_ws;                     // 32*32*1024 floats = 4 MiB
  float* pm = po + (size_t)BATCH * NCHUNK * H;  // 1024 floats
  float* pl = pm + BATCH * NCHUNK;              // 1024 floats

  attn_pass1<<<dim3(NCHUNK, BATCH), BLOCK, 0, stream>>>(query, keys, wts, po, pm, pl);
  attn_pass2<<<BATCH, 256, 0, stream>>>(po, pm, pl, ctx, wts);
}